// Round 1
// baseline (504.427 us; speedup 1.0000x reference)
//
#include <hip/hip_runtime.h>

typedef unsigned short u16;
typedef _Float16 h16;
typedef __attribute__((ext_vector_type(8))) _Float16 half8;
typedef __attribute__((ext_vector_type(2))) _Float16 half2v;
typedef __attribute__((ext_vector_type(8))) unsigned short ushort8;
typedef __attribute__((ext_vector_type(4))) float f32x4;

#define NVOX  500000
#define NBLK  7813              // ceil(500000/64): 64 rows = 4 strips of 16 per block
#define STRIP 16384             // h16 per strip arena (32768 B)

// strip-local arenas (h16 offsets / strides): hi plane rows 0..15, lo plane rows 16..31
#define AE1 0
#define SE1 40
#define AE2 1280
#define SE2 72
#define ACT 3584
#define SCT 264
#define AMR 12032
#define SMR 136

#define MFMA16(A,B,C) __builtin_amdgcn_mfma_f32_16x16x32_f16(A,B,C,0,0,0)

// light barrier: drain LDS ops only; global (B-prefetch) loads stay in flight
#define LBAR() asm volatile("s_waitcnt lgkmcnt(0)\n\ts_barrier" ::: "memory")

// ---------------- packed weight frag-pairs (f16 hi/lo) ----------------
// fragpair f (layer-local ct*KT+kt), lane l, 32 B:
//   wp[(f*64+l)*16 + j]   = hi = f16(W[k][col])   (j=0..7)
//   wp[(f*64+l)*16 + 8+j] = lo = f16(W - (float)hi)
// k = kt*32 + (l>>4)*8 + j, col = ct*16 + (l&15); zero-pad k >= K_actual.
#define F_L0   0
#define F_L1   2
#define F_L2   4
#define F_L3   8
#define F_L4   24
#define F_L5   56
#define F_L6   120
#define F_L7   136
#define F_L8   144
#define F_L9   160
#define F_L10  164
#define F_L11  166
#define F_L12  170
#define NFRAG  172              // d_ws bytes: 172*1024*2 = 352256

__device__ __forceinline__ u16 hb(h16 h) { union { h16 h; u16 u; } v; v.h = h; return v.u; }

// ---------------- weight packing (fp32 -> f16 hi/lo fragpairs) ----------------
__global__ __launch_bounds__(256) void pack_w(
    const float* w0, const float* w1, const float* w2, const float* w3, const float* w4,
    const float* w5, const float* w6, const float* w7, const float* w8, const float* w9,
    const float* w10, const float* w11, const float* w12, u16* __restrict__ packed)
{
  const float* ws[13] = {w0,w1,w2,w3,w4,w5,w6,w7,w8,w9,w10,w11,w12};
  const int Ka[13]  = {16,32,32,64,128,256,128,64,128,64,32,64,32};
  const int KT[13]  = {1,1,1,2,4,8,4,2,4,2,1,2,1};
  const int CO[13]  = {32,32,64,128,128,128,64,64,64,32,32,32,32};
  const int FO[13]  = {F_L0,F_L1,F_L2,F_L3,F_L4,F_L5,F_L6,F_L7,F_L8,F_L9,F_L10,F_L11,F_L12};
  int g = blockIdx.x * 256 + threadIdx.x;
  int f = g >> 6, lane = g & 63;
  if (f >= NFRAG) return;
  int layer = 0;
#pragma unroll
  for (int i = 1; i < 13; ++i) if (f >= FO[i]) layer = i;
  int fl = f - FO[layer];
  int kt = fl % KT[layer];
  int ct = fl / KT[layer];
  int cout = CO[layer];
  int quad = lane >> 4;
  int col  = ct * 16 + (lane & 15);
  u16 thi[8], tlo[8];
#pragma unroll
  for (int j = 0; j < 8; ++j) {
    int k = kt * 32 + quad * 8 + j;
    float w = (k < Ka[layer]) ? ws[layer][k * cout + col] : 0.f;
    h16 h = (h16)w;
    h16 l = (h16)(w - (float)h);
    thi[j] = hb(h); tlo[j] = hb(l);
  }
  u16* dst = packed + ((size_t)f * 64 + lane) * 16;
  *(ushort8*)dst       = *(const ushort8*)thi;
  *(ushort8*)(dst + 8) = *(const ushort8*)tlo;
}

// ---------------- fused backbone: M=64, 8 waves, fully balanced schedule ----------------
// Every stage = exactly 8 wave-units:
//   light layers: 1ct x 1strip units   heavy layers (L3/L4/L5): 2ct x 2strip super-units
//   L6+L7 and L9+L10 run back-to-back per wave (dual B-prefetch across the barrier)

__device__ __forceinline__ float red2(const h16* p) {   // one aligned b32 -> pair sum
  half2v v = *reinterpret_cast<const half2v*>(p);
  return (float)v.x + (float)v.y;
}

// One unit: NCT ct-tiles (stride CTS) x NSP strips, K = KT*32.
// EPI 0: relu -> hi/lo planes (+colb) | EPI 1: + pairwise-red(cat) | EPI 2: -> global fp32
template<int KT, int NCT, int CTS, int NSP, int EPI>
__device__ __forceinline__ void unitW(
    h16* __restrict__ lds, int s0, int aoff, int as,
    const h16* __restrict__ wp, int foff, int c0, int lane,
    half8 pbh, half8 pbl,
    int doff, int ds, int colb, int catoff, int cs,
    float* __restrict__ gout, int row0)
{
  const int l15 = lane & 15, quad = lane >> 4;
  const int abase = aoff + l15 * as + quad * 8;
  f32x4 acc[NSP][NCT];
#pragma unroll
  for (int sp = 0; sp < NSP; ++sp)
#pragma unroll
    for (int i = 0; i < NCT; ++i) acc[sp][i] = (f32x4){0.f,0.f,0.f,0.f};

#pragma unroll
  for (int kt = 0; kt < KT; ++kt) {
    half8 bh[NCT], bl[NCT];
#pragma unroll
    for (int i = 0; i < NCT; ++i) {
      if (kt == 0 && i == 0) { bh[0] = pbh; bl[0] = pbl; }
      else {
        const h16* fp = wp + (((size_t)(foff + (c0 + i * CTS) * KT + kt)) * 64 + lane) * 16;
        bh[i] = *(const half8*)fp;
        bl[i] = *(const half8*)(fp + 8);
      }
    }
#pragma unroll
    for (int sp = 0; sp < NSP; ++sp) {
      const h16* ab = lds + (s0 + sp) * STRIP + abase + kt * 32;
      half8 ah = *(const half8*)ab;
      half8 al = *(const half8*)(ab + 16 * as);
#pragma unroll
      for (int i = 0; i < NCT; ++i) {
        acc[sp][i] = MFMA16(al, bh[i], acc[sp][i]);
        acc[sp][i] = MFMA16(ah, bl[i], acc[sp][i]);
        acc[sp][i] = MFMA16(ah, bh[i], acc[sp][i]);
      }
    }
  }

#pragma unroll
  for (int sp = 0; sp < NSP; ++sp) {
    if (EPI <= 1) {
      h16* dstS = lds + (s0 + sp) * STRIP + doff;
      const h16* catS = lds + (s0 + sp) * STRIP + catoff;
      const int dlo = 16 * ds;
#pragma unroll
      for (int i = 0; i < NCT; ++i) {
        const int cc = (c0 + i * CTS) * 16 + l15;
#pragma unroll
        for (int r = 0; r < 4; ++r) {
          const int rr = quad * 4 + r;
          float v = acc[sp][i][r];
          v = v > 0.f ? v : 0.f;
          if (EPI == 1)
            v += red2(catS + rr * cs + 2 * cc) + red2(catS + (rr + 16) * cs + 2 * cc);
          const int idx = rr * ds + colb + cc;
          h16 h = (h16)v;
          dstS[idx]       = h;
          dstS[idx + dlo] = (h16)(v - (float)h);
        }
      }
    } else {
      const int gr0 = row0 + (s0 + sp) * 16;
#pragma unroll
      for (int i = 0; i < NCT; ++i) {
        const int cc = (c0 + i * CTS) * 16 + l15;
#pragma unroll
        for (int r = 0; r < 4; ++r) {
          const int rr = quad * 4 + r;
          float v = acc[sp][i][r];
          v = v > 0.f ? v : 0.f;
          const int grow = gr0 + rr;
          if (grow < NVOX) gout[(size_t)grow * 32 + cc] = v;
        }
      }
    }
  }
}

// prefetch next layer's first fragpair into pbh/pbl (issued BEFORE the barrier)
#define PFB(FOFF, CIDX, KT_)                                                        \
  do { const h16* _fp = wp + (((size_t)((FOFF) + (CIDX) * (KT_))) * 64 + lane) * 16; \
       pbh = *(const half8*)_fp; pbl = *(const half8*)(_fp + 8); } while (0)
#define PFB2(FOFF, CIDX, KT_)                                                       \
  do { const h16* _fp = wp + (((size_t)((FOFF) + (CIDX) * (KT_))) * 64 + lane) * 16; \
       pbh2 = *(const half8*)_fp; pbl2 = *(const half8*)(_fp + 8); } while (0)

__global__ __launch_bounds__(512, 2) void backbone(
    const float* __restrict__ feat, const h16* __restrict__ wp, float* __restrict__ out)
{
  extern __shared__ h16 lds[];   // 4 strips * 32768 B = 131072 B (dynamic)
  const int lane = threadIdx.x & 63;
  const int wv   = threadIdx.x >> 6;     // 0..7
  const int l15 = lane & 15, quad = lane >> 4;
  const int row0 = blockIdx.x * 64;

  const int sA = wv & 3;         // strip for 1-strip stages
  const int cA = wv >> 2;        // first-ct for those stages (0/1)
  const int cB = wv & 3;         // first-ct for 2-strip super-unit stages (0..3)
  const int sB = (wv >> 2) * 2;  // strip-pair base for super-unit stages (0/2)

  half8 pbh, pbl, pbh2, pbl2;

  // ---- S0: L0 (8 units = 2ct x 4strips): A from feat (K=16 pad 32) -> CT[:,0:32]
  PFB(F_L0, cA, 1);
  {
    const int grow = row0 + sA * 16 + l15;
    half8 ah = {0,0,0,0,0,0,0,0}, al = {0,0,0,0,0,0,0,0};
    if (quad < 2 && grow < NVOX) {
      const float* s = feat + (size_t)grow * 16 + quad * 8;
      f32x4 u0 = *(const f32x4*)s;
      f32x4 u1 = *(const f32x4*)(s + 4);
      h16 th[8], tl[8];
#pragma unroll
      for (int j = 0; j < 4; ++j) {
        h16 h = (h16)u0[j]; th[j] = h; tl[j] = (h16)(u0[j] - (float)h);
      }
#pragma unroll
      for (int j = 0; j < 4; ++j) {
        h16 h = (h16)u1[j]; th[4+j] = h; tl[4+j] = (h16)(u1[j] - (float)h);
      }
      ah = *(const half8*)th; al = *(const half8*)tl;
    }
    f32x4 a = {0.f,0.f,0.f,0.f};
    a = MFMA16(al, pbh, a); a = MFMA16(ah, pbl, a); a = MFMA16(ah, pbh, a);
    h16* dstS = lds + sA * STRIP + ACT;
#pragma unroll
    for (int r = 0; r < 4; ++r) {
      const int rr = quad * 4 + r;
      float v = a[r] > 0.f ? a[r] : 0.f;
      const int idx = rr * SCT + cA * 16 + l15;
      h16 h = (h16)v;
      dstS[idx]            = h;
      dstS[idx + 16 * SCT] = (h16)(v - (float)h);
    }
  }
  PFB(F_L1, cA, 1);
  LBAR();

  // ---- S1: L1 (8 = 2ct x 4s): x(CT[0:32]) -> E1
  unitW<1,1,1,1,0>(lds, sA, ACT, SCT, wp, F_L1, cA, lane, pbh, pbl, AE1, SE1, 0, 0, 0, nullptr, 0);
  PFB(F_L2, cA, 1);
  LBAR();

  // ---- S2: L2 (8 = 2cp x 4s, cts {cA,cA+2}): e1(E1) -> E2
  unitW<1,2,2,1,0>(lds, sA, AE1, SE1, wp, F_L2, cA, lane, pbh, pbl, AE2, SE2, 0, 0, 0, nullptr, 0);
  PFB(F_L3, cB, 2);
  LBAR();

  // ---- S3: L3 (8 super = 4cp x 2sp, cts {cB,cB+4}, strips {sB,sB+1}): e2(E2) -> CT[:,0:128]
  unitW<2,2,4,2,0>(lds, sB, AE2, SE2, wp, F_L3, cB, lane, pbh, pbl, ACT, SCT, 0, 0, 0, nullptr, 0);
  PFB(F_L4, cB, 4);
  LBAR();

  // ---- S4: L4 (8 super): e3(CT[0:128]) -> CT[:,128:256]
  unitW<4,2,4,2,0>(lds, sB, ACT, SCT, wp, F_L4, cB, lane, pbh, pbl, ACT, SCT, 128, 0, 0, nullptr, 0);
  PFB(F_L5, cB, 8);
  LBAR();

  // ---- S5: L5 (8 super): merge3(CT[0:256]) + red -> MR[:,0:128]
  unitW<8,2,4,2,1>(lds, sB, ACT, SCT, wp, F_L5, cB, lane, pbh, pbl, AMR, SMR, 0, ACT, SCT, nullptr, 0);
  PFB (F_L6, cA, 4);
  PFB2(F_L7, cA, 2);
  LBAR();

  // ---- S6: L6 (8 = 2cp x 4s): x2(MR[0:128]) -> CT[:,0:64]
  //          L7 (8 = 2cp x 4s): lat2(E2)      -> CT[:,64:128]   (back-to-back per wave)
  unitW<4,2,2,1,0>(lds, sA, AMR, SMR, wp, F_L6, cA, lane, pbh,  pbl,  ACT, SCT, 0,  0, 0, nullptr, 0);
  unitW<2,2,2,1,0>(lds, sA, AE2, SE2, wp, F_L7, cA, lane, pbh2, pbl2, ACT, SCT, 64, 0, 0, nullptr, 0);
  PFB(F_L8, cA, 4);
  LBAR();

  // ---- S7: L8 (8 = 2cp x 4s): merge2(CT[0:128]) + red -> MR[:,0:64]
  unitW<4,2,2,1,1>(lds, sA, ACT, SCT, wp, F_L8, cA, lane, pbh, pbl, AMR, SMR, 0, ACT, SCT, nullptr, 0);
  PFB (F_L9,  cA, 2);
  PFB2(F_L10, cA, 1);
  LBAR();

  // ---- S8: L9 (8 = 2ct x 4s): x1(MR[0:64]) -> CT[:,0:32]
  //          L10 (8 = 2ct x 4s): lat1(E1)    -> CT[:,32:64]    (back-to-back per wave)
  unitW<2,1,1,1,0>(lds, sA, AMR, SMR, wp, F_L9,  cA, lane, pbh,  pbl,  ACT, SCT, 0,  0, 0, nullptr, 0);
  unitW<1,1,1,1,0>(lds, sA, AE1, SE1, wp, F_L10, cA, lane, pbh2, pbl2, ACT, SCT, 32, 0, 0, nullptr, 0);
  PFB(F_L11, cA, 2);
  LBAR();

  // ---- S9: L11 (8 = 2ct x 4s): merge1(CT[0:64]) + red -> MR[:,0:32]
  unitW<2,1,1,1,1>(lds, sA, ACT, SCT, wp, F_L11, cA, lane, pbh, pbl, AMR, SMR, 0, ACT, SCT, nullptr, 0);
  PFB(F_L12, cA, 1);
  LBAR();

  // ---- S10: L12 (8 = 2ct x 4s): out(MR[0:32]) -> global fp32 [N,32]
  unitW<1,1,1,1,2>(lds, sA, AMR, SMR, wp, F_L12, cA, lane, pbh, pbl, 0, 0, 0, 0, 0, out, row0);
}

extern "C" void kernel_launch(void* const* d_in, const int* in_sizes, int n_in,
                              void* d_out, int out_size, void* d_ws, size_t ws_size,
                              hipStream_t stream) {
  (void)in_sizes; (void)n_in; (void)out_size; (void)ws_size;
  u16* packed = (u16*)d_ws;   // 352256 B

  static bool att_set = false;
  if (!att_set) {
    hipFuncSetAttribute((const void*)backbone,
                        hipFuncAttributeMaxDynamicSharedMemorySize, 131072);
    att_set = true;
  }

  // order: in, enc1, enc2, enc3, lat3, merge3, up3, lat2, merge2, up2, lat1, merge1, up1
  hipLaunchKernelGGL(pack_w, dim3(43), dim3(256), 0, stream,
      (const float*)d_in[2],  (const float*)d_in[3],  (const float*)d_in[4],
      (const float*)d_in[5],  (const float*)d_in[8],  (const float*)d_in[11],
      (const float*)d_in[14], (const float*)d_in[7],  (const float*)d_in[10],
      (const float*)d_in[13], (const float*)d_in[6],  (const float*)d_in[9],
      (const float*)d_in[12], packed);

  hipLaunchKernelGGL(backbone, dim3(NBLK), dim3(512), 131072, stream,
                     (const float*)d_in[0], (const h16*)packed, (float*)d_out);
}

// Round 2
// 449.090 us; speedup vs baseline: 1.1232x; 1.1232x over previous
//
#include <hip/hip_runtime.h>

typedef unsigned short u16;
typedef unsigned int u32;
typedef _Float16 h16;
typedef __attribute__((ext_vector_type(4))) _Float16 half4;
typedef __attribute__((ext_vector_type(8))) _Float16 half8;
typedef __attribute__((ext_vector_type(8))) unsigned short ushort8;
typedef __attribute__((ext_vector_type(4))) float f32x4;

#define NPAIRS 15625            // 500000 / 32: each block = 8 waves = 2 strips (M=32)
#define STRIPO 11648            // h16 per strip arena (23296 B)

// Interleaved hi/lo layout: element (row r, col c) of a buffer with stride S:
//   hi at base + r*S + 2c, lo at base + r*S + 2c + 1.
// Strides = 2*cols + 8  ->  dword-stride == 4 (mod 32): conflict-free b128/b32/b64.
#define AE1 0                   // 32 cols, 16 rows
#define SE1 72
#define AE2 1152                // 64 cols
#define SE2 136
#define ACT 3328                // 256 cols
#define SCT 520
#define AMR 3584                // MR (<=128 cols) ALIASED into CT cols [128:256)
#define SMR 520                 //   (h16 [256:512) of each CT row); written S5 post-barrier

#define MFMA16(A,B,C) __builtin_amdgcn_mfma_f32_16x16x32_f16(A,B,C,0,0,0)

// light barrier: drain LDS ops only; global (B-prefetch) loads stay in flight
#define LBAR() asm volatile("s_waitcnt lgkmcnt(0)\n\ts_barrier" ::: "memory")

// ---------------- packed weight frag-pairs (f16 hi/lo, planar) ----------------
#define F_L0   0
#define F_L1   2
#define F_L2   4
#define F_L3   8
#define F_L4   24
#define F_L5   56
#define F_L6   120
#define F_L7   136
#define F_L8   144
#define F_L9   160
#define F_L10  164
#define F_L11  166
#define F_L12  170
#define NFRAG  172              // d_ws bytes: 172*1024*2 = 352256

__device__ __forceinline__ u16 hb(h16 h) { union { h16 h; u16 u; } v; v.h = h; return v.u; }

__global__ __launch_bounds__(256) void pack_w(
    const float* w0, const float* w1, const float* w2, const float* w3, const float* w4,
    const float* w5, const float* w6, const float* w7, const float* w8, const float* w9,
    const float* w10, const float* w11, const float* w12, u16* __restrict__ packed)
{
  const float* ws[13] = {w0,w1,w2,w3,w4,w5,w6,w7,w8,w9,w10,w11,w12};
  const int Ka[13]  = {16,32,32,64,128,256,128,64,128,64,32,64,32};
  const int KT[13]  = {1,1,1,2,4,8,4,2,4,2,1,2,1};
  const int CO[13]  = {32,32,64,128,128,128,64,64,64,32,32,32,32};
  const int FO[13]  = {F_L0,F_L1,F_L2,F_L3,F_L4,F_L5,F_L6,F_L7,F_L8,F_L9,F_L10,F_L11,F_L12};
  int g = blockIdx.x * 256 + threadIdx.x;
  int f = g >> 6, lane = g & 63;
  if (f >= NFRAG) return;
  int layer = 0;
#pragma unroll
  for (int i = 1; i < 13; ++i) if (f >= FO[i]) layer = i;
  int fl = f - FO[layer];
  int kt = fl % KT[layer];
  int ct = fl / KT[layer];
  int cout = CO[layer];
  int quad = lane >> 4;
  int col  = ct * 16 + (lane & 15);
  u16 thi[8], tlo[8];
#pragma unroll
  for (int j = 0; j < 8; ++j) {
    int k = kt * 32 + quad * 8 + j;
    float w = (k < Ka[layer]) ? ws[layer][k * cout + col] : 0.f;
    h16 h = (h16)w;
    h16 l = (h16)(w - (float)h);
    thi[j] = hb(h); tlo[j] = hb(l);
  }
  u16* dst = packed + ((size_t)f * 64 + lane) * 16;
  *(ushort8*)dst       = *(const ushort8*)thi;
  *(ushort8*)(dst + 8) = *(const ushort8*)tlo;
}

// ---------------- fused backbone ----------------

__device__ __forceinline__ void packw(h16* dst, int idx2, float v) {
  h16 h = (h16)v;
  h16 l = (h16)(v - (float)h);
  union { u16 s[2]; u32 u; } z;
  z.s[0] = hb(h); z.s[1] = hb(l);
  *reinterpret_cast<u32*>(dst + idx2) = z.u;     // one b32 write: hi|lo packed
}

__device__ __forceinline__ float red2i(const h16* cat, int cs, int rr, int cc) {
  // cat[2c] + cat[2c+1] (hi+lo each) = one b64 read of 4 interleaved h16
  half4 v = *reinterpret_cast<const half4*>(cat + rr * cs + 4 * cc);
  return (float)v.x + (float)v.y + (float)v.z + (float)v.w;
}

// One layer, one ct tile, both strips. EPI 0: relu->LDS | 1: +pair-red(cat) | 2: ->global
// BAR=1: block barrier between (all LDS reads) and (epilogue writes) — for MR/CT aliasing.
template<int KT, int EPI, int BAR>
__device__ __forceinline__ void layerW(
    const h16* __restrict__ asrc, int as,
    const h16* __restrict__ wp, int foff, int ct, int lane,
    half8 pbh, half8 pbl,
    h16* dst, int ds, int colb, const h16* cat, int cs,
    float* __restrict__ gout, int row0)
{
  const int l15 = lane & 15, quad = lane >> 4;
  const int abase = l15 * as + quad * 16;
  f32x4 a0 = {0.f,0.f,0.f,0.f}, a1 = {0.f,0.f,0.f,0.f};
#pragma unroll
  for (int kt = 0; kt < KT; ++kt) {
    half8 bhv, blv;
    if (kt == 0) { bhv = pbh; blv = pbl; }
    else {
      const h16* fp = wp + (((size_t)(foff + ct * KT + kt)) * 64 + lane) * 16;
      bhv = *(const half8*)fp;
      blv = *(const half8*)(fp + 8);
    }
    const h16* p0 = asrc + abase + kt * 64;
    const h16* p1 = p0 + STRIPO;
    half8 q0a = *(const half8*)p0, q0b = *(const half8*)(p0 + 8);
    half8 q1a = *(const half8*)p1, q1b = *(const half8*)(p1 + 8);
    half8 ah0 = __builtin_shufflevector(q0a, q0b, 0,2,4,6,8,10,12,14);
    half8 al0 = __builtin_shufflevector(q0a, q0b, 1,3,5,7,9,11,13,15);
    half8 ah1 = __builtin_shufflevector(q1a, q1b, 0,2,4,6,8,10,12,14);
    half8 al1 = __builtin_shufflevector(q1a, q1b, 1,3,5,7,9,11,13,15);
    a0 = MFMA16(al0, bhv, a0); a0 = MFMA16(ah0, blv, a0); a0 = MFMA16(ah0, bhv, a0);
    a1 = MFMA16(al1, bhv, a1); a1 = MFMA16(ah1, blv, a1); a1 = MFMA16(ah1, bhv, a1);
  }
  const int cc = ct * 16 + l15;
  float v0r[4], v1r[4];
#pragma unroll
  for (int r = 0; r < 4; ++r) {
    const int rr = quad * 4 + r;
    float v0 = a0[r] > 0.f ? a0[r] : 0.f;
    float v1 = a1[r] > 0.f ? a1[r] : 0.f;
    if (EPI == 1) {
      v0 += red2i(cat, cs, rr, cc);
      v1 += red2i(cat + STRIPO, cs, rr, cc);
    }
    v0r[r] = v0; v1r[r] = v1;
  }
  if (BAR) LBAR();                 // all reads of aliased region done before any write
  if (EPI <= 1) {
#pragma unroll
    for (int r = 0; r < 4; ++r) {
      const int rr = quad * 4 + r;
      const int idx2 = rr * ds + 2 * (colb + cc);
      packw(dst, idx2, v0r[r]);
      packw(dst + STRIPO, idx2, v1r[r]);
    }
  } else {
#pragma unroll
    for (int r = 0; r < 4; ++r) {
      const int rr = quad * 4 + r;
      gout[(size_t)(row0 + rr) * 32 + cc]      = v0r[r];
      gout[(size_t)(row0 + 16 + rr) * 32 + cc] = v1r[r];
    }
  }
}

#define PFB(FOFF, CIDX, KT_)                                                        \
  do { const h16* _fp = wp + (((size_t)((FOFF) + (CIDX) * (KT_))) * 64 + lane) * 16; \
       pbh = *(const half8*)_fp; pbl = *(const half8*)(_fp + 8); } while (0)

__global__ __launch_bounds__(512, 6) void backbone(
    const float* __restrict__ feat, const h16* __restrict__ wp, float* __restrict__ out)
{
  __shared__ h16 lds[2 * STRIPO];  // 46592 B -> 3 blocks/CU
  const int lane = threadIdx.x & 63;
  const int wv   = threadIdx.x >> 6;     // 0..7
  const int l15 = lane & 15, quad = lane >> 4;
  const int row0 = blockIdx.x * 32;

  h16* E1 = lds + AE1;
  h16* E2 = lds + AE2;
  h16* CT = lds + ACT;
  h16* MR = lds + AMR;

  half8 pbh, pbl;

  // ---- S0: L0 (COT=2, waves 0-1): A from feat (K=16 pad 32) -> CT[:,0:32]
  if (wv < 2) {
    PFB(F_L0, wv, 1);
    h16 th0[8] = {0,0,0,0,0,0,0,0}, tl0[8] = {0,0,0,0,0,0,0,0};
    h16 th1[8] = {0,0,0,0,0,0,0,0}, tl1[8] = {0,0,0,0,0,0,0,0};
    if (quad < 2) {
      const float* s0 = feat + (size_t)(row0 + l15) * 16 + quad * 8;
      const float* s1 = feat + (size_t)(row0 + 16 + l15) * 16 + quad * 8;
      f32x4 u0a = *(const f32x4*)s0, u0b = *(const f32x4*)(s0 + 4);
      f32x4 u1a = *(const f32x4*)s1, u1b = *(const f32x4*)(s1 + 4);
#pragma unroll
      for (int j = 0; j < 4; ++j) {
        h16 h;
        h = (h16)u0a[j]; th0[j]   = h; tl0[j]   = (h16)(u0a[j] - (float)h);
        h = (h16)u0b[j]; th0[4+j] = h; tl0[4+j] = (h16)(u0b[j] - (float)h);
        h = (h16)u1a[j]; th1[j]   = h; tl1[j]   = (h16)(u1a[j] - (float)h);
        h = (h16)u1b[j]; th1[4+j] = h; tl1[4+j] = (h16)(u1b[j] - (float)h);
      }
    }
    half8 ah0 = *(const half8*)th0, al0 = *(const half8*)tl0;
    half8 ah1 = *(const half8*)th1, al1 = *(const half8*)tl1;
    f32x4 a0 = {0.f,0.f,0.f,0.f}, a1 = {0.f,0.f,0.f,0.f};
    a0 = MFMA16(al0, pbh, a0); a0 = MFMA16(ah0, pbl, a0); a0 = MFMA16(ah0, pbh, a0);
    a1 = MFMA16(al1, pbh, a1); a1 = MFMA16(ah1, pbl, a1); a1 = MFMA16(ah1, pbh, a1);
#pragma unroll
    for (int r = 0; r < 4; ++r) {
      const int rr = quad * 4 + r;
      const int idx2 = rr * SCT + 2 * (wv * 16 + l15);
      packw(CT,          idx2, a0[r] > 0.f ? a0[r] : 0.f);
      packw(CT + STRIPO, idx2, a1[r] > 0.f ? a1[r] : 0.f);
    }
    PFB(F_L1, wv, 1);
  }
  LBAR();

  // ---- S1: L1 (COT=2): x0(CT[0:32]) -> E1
  if (wv < 2) {
    layerW<1,0,0>(CT,SCT, wp, F_L1, wv, lane, pbh,pbl, E1,SE1,0, nullptr,0, nullptr,0);
  }
  if (wv < 4) PFB(F_L2, wv, 1);
  LBAR();

  // ---- S2: L2 (COT=4): e1(E1) -> E2
  if (wv < 4) {
    layerW<1,0,0>(E1,SE1, wp, F_L2, wv, lane, pbh,pbl, E2,SE2,0, nullptr,0, nullptr,0);
  }
  PFB(F_L3, wv, 2);
  LBAR();

  // ---- S3: L3 (COT=8): e2(E2) -> CT[:,0:128]
  layerW<2,0,0>(E2,SE2, wp, F_L3, wv, lane, pbh,pbl, CT,SCT,0, nullptr,0, nullptr,0);
  PFB(F_L4, wv, 4);
  LBAR();

  // ---- S4: L4 (COT=8): e3(CT[0:128]) -> CT[:,128:256]
  layerW<4,0,0>(CT,SCT, wp, F_L4, wv, lane, pbh,pbl, CT,SCT,128, nullptr,0, nullptr,0);
  PFB(F_L5, wv, 8);
  LBAR();

  // ---- S5: L5 (COT=8): merge3(CT[0:256]) + red -> MR[:,0:128]  (MR aliases CT[128:256):
  //         mid-stage barrier inside layerW orders all CT reads before MR writes)
  layerW<8,1,1>(CT,SCT, wp, F_L5, wv, lane, pbh,pbl, MR,SMR,0, CT,SCT, nullptr,0);
  if (wv < 4) PFB(F_L6, wv, 4); else PFB(F_L7, wv - 4, 2);
  LBAR();

  // ---- S6 (fused): L6 (COT=4, waves 0-3): x2(MR[0:128]) -> CT[:,0:64]
  //                  L7 (COT=4, waves 4-7): lat2(E2)      -> CT[:,64:128]
  if (wv < 4) {
    layerW<4,0,0>(MR,SMR, wp, F_L6, wv, lane, pbh,pbl, CT,SCT,0,  nullptr,0, nullptr,0);
  } else {
    layerW<2,0,0>(E2,SE2, wp, F_L7, wv - 4, lane, pbh,pbl, CT,SCT,64, nullptr,0, nullptr,0);
  }
  if (wv < 4) PFB(F_L8, wv, 4);
  LBAR();

  // ---- S7: L8 (COT=4): merge2(CT[0:128]) + red -> MR[:,0:64]  (write region CT[128:192):
  //         disjoint from this stage's reads -> no mid barrier)
  if (wv < 4) {
    layerW<4,1,0>(CT,SCT, wp, F_L8, wv, lane, pbh,pbl, MR,SMR,0, CT,SCT, nullptr,0);
  }
  if (wv < 2) PFB(F_L9, wv, 2);
  else if (wv < 4) PFB(F_L10, wv - 2, 1);
  LBAR();

  // ---- S8 (fused): L9 (COT=2, waves 0-1): x1(MR[0:64]) -> CT[:,0:32]
  //                  L10 (COT=2, waves 2-3): lat1(E1)    -> CT[:,32:64]
  if (wv < 2) {
    layerW<2,0,0>(MR,SMR, wp, F_L9, wv, lane, pbh,pbl, CT,SCT,0,  nullptr,0, nullptr,0);
  } else if (wv < 4) {
    layerW<1,0,0>(E1,SE1, wp, F_L10, wv - 2, lane, pbh,pbl, CT,SCT,32, nullptr,0, nullptr,0);
  }
  if (wv < 2) PFB(F_L11, wv, 2);
  LBAR();

  // ---- S9: L11 (COT=2): merge1(CT[0:64]) + red -> MR[:,0:32]  (write CT[128:160): disjoint)
  if (wv < 2) {
    layerW<2,1,0>(CT,SCT, wp, F_L11, wv, lane, pbh,pbl, MR,SMR,0, CT,SCT, nullptr,0);
    PFB(F_L12, wv, 1);
  }
  LBAR();

  // ---- S10: L12 (COT=2): out(MR[0:32]) -> global fp32 [N,32]
  if (wv < 2) {
    layerW<1,2,0>(MR,SMR, wp, F_L12, wv, lane, pbh,pbl, nullptr,0,0, nullptr,0, out, row0);
  }
}

extern "C" void kernel_launch(void* const* d_in, const int* in_sizes, int n_in,
                              void* d_out, int out_size, void* d_ws, size_t ws_size,
                              hipStream_t stream) {
  (void)in_sizes; (void)n_in; (void)out_size; (void)ws_size;
  u16* packed = (u16*)d_ws;   // 352256 B

  // order: in, enc1, enc2, enc3, lat3, merge3, up3, lat2, merge2, up2, lat1, merge1, up1
  hipLaunchKernelGGL(pack_w, dim3(43), dim3(256), 0, stream,
      (const float*)d_in[2],  (const float*)d_in[3],  (const float*)d_in[4],
      (const float*)d_in[5],  (const float*)d_in[8],  (const float*)d_in[11],
      (const float*)d_in[14], (const float*)d_in[7],  (const float*)d_in[10],
      (const float*)d_in[13], (const float*)d_in[6],  (const float*)d_in[9],
      (const float*)d_in[12], packed);

  hipLaunchKernelGGL(backbone, dim3(NPAIRS), dim3(512), 0, stream,
                     (const float*)d_in[0], (const h16*)packed, (float*)d_out);
}

// Round 3
// 432.311 us; speedup vs baseline: 1.1668x; 1.0388x over previous
//
#include <hip/hip_runtime.h>

typedef unsigned short u16;
typedef unsigned int u32;
typedef _Float16 h16;
typedef __attribute__((ext_vector_type(2))) _Float16 half2v;
typedef __attribute__((ext_vector_type(8))) _Float16 half8;
typedef __attribute__((ext_vector_type(8))) unsigned short ushort8;
typedef __attribute__((ext_vector_type(4))) float f32x4;

#define NPAIRS 15625            // 500000 / 32: each block = 8 waves = 2 strips (M=32)
#define STRIPH 12032            // h16 per strip arena (24064 B); block total 48128 B

// Planar hi/lo layout: value (row r, col c) of buffer with stride S:
//   hi at base + r*S + c  (rows 0..15), lo at base + (16+r)*S + c.
// No deinterleave: A-fragments are direct b128 reads of 8 contiguous h16.
#define AE1 0                   // 32 cols
#define SE1 40
#define AE2 1280                // 64 cols
#define SE2 72
#define ACT 3584                // 256 cols
#define SCT 264
#define AMR 3712                // MR (<=128 cols) ALIASED into CT cols [128:256)
#define SMR 264                 //   written S5 only after the mid-stage barrier

#define MFMA16(A,B,C) __builtin_amdgcn_mfma_f32_16x16x32_f16(A,B,C,0,0,0)

// light barrier: drain LDS ops only; global (B-prefetch) loads stay in flight
#define LBAR() asm volatile("s_waitcnt lgkmcnt(0)\n\ts_barrier" ::: "memory")

// ---------------- packed weight frag-pairs (f16 hi/lo, planar) ----------------
#define F_L0   0
#define F_L1   2
#define F_L2   4
#define F_L3   8
#define F_L4   24
#define F_L5   56
#define F_L6   120
#define F_L7   136
#define F_L8   144
#define F_L9   160
#define F_L10  164
#define F_L11  166
#define F_L12  170
#define NFRAG  172              // d_ws bytes: 172*1024*2 = 352256

__device__ __forceinline__ u16 hb(h16 h) { union { h16 h; u16 u; } v; v.h = h; return v.u; }

__global__ __launch_bounds__(256) void pack_w(
    const float* w0, const float* w1, const float* w2, const float* w3, const float* w4,
    const float* w5, const float* w6, const float* w7, const float* w8, const float* w9,
    const float* w10, const float* w11, const float* w12, u16* __restrict__ packed)
{
  const float* ws[13] = {w0,w1,w2,w3,w4,w5,w6,w7,w8,w9,w10,w11,w12};
  const int Ka[13]  = {16,32,32,64,128,256,128,64,128,64,32,64,32};
  const int KT[13]  = {1,1,1,2,4,8,4,2,4,2,1,2,1};
  const int CO[13]  = {32,32,64,128,128,128,64,64,64,32,32,32,32};
  const int FO[13]  = {F_L0,F_L1,F_L2,F_L3,F_L4,F_L5,F_L6,F_L7,F_L8,F_L9,F_L10,F_L11,F_L12};
  int g = blockIdx.x * 256 + threadIdx.x;
  int f = g >> 6, lane = g & 63;
  if (f >= NFRAG) return;
  int layer = 0;
#pragma unroll
  for (int i = 1; i < 13; ++i) if (f >= FO[i]) layer = i;
  int fl = f - FO[layer];
  int kt = fl % KT[layer];
  int ct = fl / KT[layer];
  int cout = CO[layer];
  int quad = lane >> 4;
  int col  = ct * 16 + (lane & 15);
  u16 thi[8], tlo[8];
#pragma unroll
  for (int j = 0; j < 8; ++j) {
    int k = kt * 32 + quad * 8 + j;
    float w = (k < Ka[layer]) ? ws[layer][k * cout + col] : 0.f;
    h16 h = (h16)w;
    h16 l = (h16)(w - (float)h);
    thi[j] = hb(h); tlo[j] = hb(l);
  }
  u16* dst = packed + ((size_t)f * 64 + lane) * 16;
  *(ushort8*)dst       = *(const ushort8*)thi;
  *(ushort8*)(dst + 8) = *(const ushort8*)tlo;
}

// ---------------- fused backbone ----------------

__device__ __forceinline__ void splitw(h16* dst, int idx, int dlo, float v) {
  h16 h = (h16)v;
  dst[idx]       = h;
  dst[idx + dlo] = (h16)(v - (float)h);
}

__device__ __forceinline__ float red2p(const h16* cat, int cs, int rr, int cc) {
  // (cat[2c]+cat[2c+1]) hi-plane pair + lo-plane pair: two b32 reads
  half2v hp = *reinterpret_cast<const half2v*>(cat + rr * cs + 2 * cc);
  half2v lp = *reinterpret_cast<const half2v*>(cat + (rr + 16) * cs + 2 * cc);
  return (float)hp.x + (float)hp.y + (float)lp.x + (float)lp.y;
}

// One layer, one ct tile, both strips. EPI 0: relu->LDS | 1: +pair-red(cat) | 2: ->global
// BAR=1: full-block barrier between (all LDS reads) and (epilogue writes) — MR/CT aliasing.
template<int KT, int EPI, int BAR>
__device__ __forceinline__ void layerW(
    const h16* __restrict__ asrc, int as,
    const h16* __restrict__ wp, int foff, int ct, int lane,
    half8 pbh, half8 pbl,
    h16* dst, int ds, int colb, const h16* cat, int cs,
    float* __restrict__ gout, int row0)
{
  const int l15 = lane & 15, quad = lane >> 4;
  const int abase = l15 * as + quad * 8;
  const int alo = 16 * as;
  f32x4 a0 = {0.f,0.f,0.f,0.f}, a1 = {0.f,0.f,0.f,0.f};
#pragma unroll
  for (int kt = 0; kt < KT; ++kt) {
    half8 bhv, blv;
    if (kt == 0) { bhv = pbh; blv = pbl; }
    else {
      const h16* fp = wp + (((size_t)(foff + ct * KT + kt)) * 64 + lane) * 16;
      bhv = *(const half8*)fp;
      blv = *(const half8*)(fp + 8);
    }
    const h16* p0 = asrc + abase + kt * 32;
    const h16* p1 = p0 + STRIPH;
    half8 ah0 = *(const half8*)p0;
    half8 al0 = *(const half8*)(p0 + alo);
    half8 ah1 = *(const half8*)p1;
    half8 al1 = *(const half8*)(p1 + alo);
    a0 = MFMA16(al0, bhv, a0); a0 = MFMA16(ah0, blv, a0); a0 = MFMA16(ah0, bhv, a0);
    a1 = MFMA16(al1, bhv, a1); a1 = MFMA16(ah1, blv, a1); a1 = MFMA16(ah1, bhv, a1);
  }
  const int cc = ct * 16 + l15;
  float v0r[4], v1r[4];
#pragma unroll
  for (int r = 0; r < 4; ++r) {
    const int rr = quad * 4 + r;
    float v0 = a0[r] > 0.f ? a0[r] : 0.f;
    float v1 = a1[r] > 0.f ? a1[r] : 0.f;
    if (EPI == 1) {
      v0 += red2p(cat, cs, rr, cc);
      v1 += red2p(cat + STRIPH, cs, rr, cc);
    }
    v0r[r] = v0; v1r[r] = v1;
  }
  if (BAR) LBAR();                 // all reads of aliased region done before any write
  if (EPI <= 1) {
    const int dlo = 16 * ds;
#pragma unroll
    for (int r = 0; r < 4; ++r) {
      const int rr = quad * 4 + r;
      const int idx = rr * ds + colb + cc;
      splitw(dst,          idx, dlo, v0r[r]);
      splitw(dst + STRIPH, idx, dlo, v1r[r]);
    }
  } else {
#pragma unroll
    for (int r = 0; r < 4; ++r) {
      const int rr = quad * 4 + r;
      gout[(size_t)(row0 + rr) * 32 + cc]      = v0r[r];
      gout[(size_t)(row0 + 16 + rr) * 32 + cc] = v1r[r];
    }
  }
}

#define PFB(FOFF, CIDX, KT_)                                                        \
  do { const h16* _fp = wp + (((size_t)((FOFF) + (CIDX) * (KT_))) * 64 + lane) * 16; \
       pbh = *(const half8*)_fp; pbl = *(const half8*)(_fp + 8); } while (0)

__global__ __launch_bounds__(512, 6) void backbone(
    const float* __restrict__ feat, const h16* __restrict__ wp, float* __restrict__ out)
{
  __shared__ h16 lds[2 * STRIPH];  // 48128 B -> 3 blocks/CU (24 waves)
  const int lane = threadIdx.x & 63;
  const int wv   = threadIdx.x >> 6;     // 0..7
  const int l15 = lane & 15, quad = lane >> 4;
  const int row0 = blockIdx.x * 32;

  h16* E1 = lds + AE1;
  h16* E2 = lds + AE2;
  h16* CT = lds + ACT;
  h16* MR = lds + AMR;

  half8 pbh, pbl;

  // ---- S0: L0 (COT=2, waves 0-1): A from feat (K=16 pad 32) -> CT[:,0:32]
  if (wv < 2) {
    PFB(F_L0, wv, 1);
    h16 th0[8] = {0,0,0,0,0,0,0,0}, tl0[8] = {0,0,0,0,0,0,0,0};
    h16 th1[8] = {0,0,0,0,0,0,0,0}, tl1[8] = {0,0,0,0,0,0,0,0};
    if (quad < 2) {
      const float* s0 = feat + (size_t)(row0 + l15) * 16 + quad * 8;
      const float* s1 = feat + (size_t)(row0 + 16 + l15) * 16 + quad * 8;
      f32x4 u0a = *(const f32x4*)s0, u0b = *(const f32x4*)(s0 + 4);
      f32x4 u1a = *(const f32x4*)s1, u1b = *(const f32x4*)(s1 + 4);
#pragma unroll
      for (int j = 0; j < 4; ++j) {
        h16 h;
        h = (h16)u0a[j]; th0[j]   = h; tl0[j]   = (h16)(u0a[j] - (float)h);
        h = (h16)u0b[j]; th0[4+j] = h; tl0[4+j] = (h16)(u0b[j] - (float)h);
        h = (h16)u1a[j]; th1[j]   = h; tl1[j]   = (h16)(u1a[j] - (float)h);
        h = (h16)u1b[j]; th1[4+j] = h; tl1[4+j] = (h16)(u1b[j] - (float)h);
      }
    }
    half8 ah0 = *(const half8*)th0, al0 = *(const half8*)tl0;
    half8 ah1 = *(const half8*)th1, al1 = *(const half8*)tl1;
    f32x4 a0 = {0.f,0.f,0.f,0.f}, a1 = {0.f,0.f,0.f,0.f};
    a0 = MFMA16(al0, pbh, a0); a0 = MFMA16(ah0, pbl, a0); a0 = MFMA16(ah0, pbh, a0);
    a1 = MFMA16(al1, pbh, a1); a1 = MFMA16(ah1, pbl, a1); a1 = MFMA16(ah1, pbh, a1);
    const int dlo = 16 * SCT;
#pragma unroll
    for (int r = 0; r < 4; ++r) {
      const int rr = quad * 4 + r;
      const int idx = rr * SCT + wv * 16 + l15;
      splitw(CT,          idx, dlo, a0[r] > 0.f ? a0[r] : 0.f);
      splitw(CT + STRIPH, idx, dlo, a1[r] > 0.f ? a1[r] : 0.f);
    }
    PFB(F_L1, wv, 1);
  }
  LBAR();

  // ---- S1: L1 (COT=2): x0(CT[0:32]) -> E1
  if (wv < 2) {
    layerW<1,0,0>(CT,SCT, wp, F_L1, wv, lane, pbh,pbl, E1,SE1,0, nullptr,0, nullptr,0);
  }
  if (wv < 4) PFB(F_L2, wv, 1);
  LBAR();

  // ---- S2: L2 (COT=4): e1(E1) -> E2
  if (wv < 4) {
    layerW<1,0,0>(E1,SE1, wp, F_L2, wv, lane, pbh,pbl, E2,SE2,0, nullptr,0, nullptr,0);
  }
  PFB(F_L3, wv, 2);
  LBAR();

  // ---- S3: L3 (COT=8): e2(E2) -> CT[:,0:128]
  layerW<2,0,0>(E2,SE2, wp, F_L3, wv, lane, pbh,pbl, CT,SCT,0, nullptr,0, nullptr,0);
  PFB(F_L4, wv, 4);
  LBAR();

  // ---- S4: L4 (COT=8): e3(CT[0:128]) -> CT[:,128:256]
  layerW<4,0,0>(CT,SCT, wp, F_L4, wv, lane, pbh,pbl, CT,SCT,128, nullptr,0, nullptr,0);
  PFB(F_L5, wv, 8);
  LBAR();

  // ---- S5: L5 (COT=8): merge3(CT[0:256]) + red -> MR[:,0:128]  (MR aliases CT[128:256):
  //         mid-stage barrier inside layerW orders all CT reads before MR writes)
  layerW<8,1,1>(CT,SCT, wp, F_L5, wv, lane, pbh,pbl, MR,SMR,0, CT,SCT, nullptr,0);
  if (wv < 4) PFB(F_L6, wv, 4); else PFB(F_L7, wv - 4, 2);
  LBAR();

  // ---- S6 (fused): L6 (COT=4, waves 0-3): x2(MR[0:128]) -> CT[:,0:64]
  //                  L7 (COT=4, waves 4-7): lat2(E2)      -> CT[:,64:128]
  if (wv < 4) {
    layerW<4,0,0>(MR,SMR, wp, F_L6, wv, lane, pbh,pbl, CT,SCT,0,  nullptr,0, nullptr,0);
  } else {
    layerW<2,0,0>(E2,SE2, wp, F_L7, wv - 4, lane, pbh,pbl, CT,SCT,64, nullptr,0, nullptr,0);
  }
  if (wv < 4) PFB(F_L8, wv, 4);
  LBAR();

  // ---- S7: L8 (COT=4): merge2(CT[0:128]) + red -> MR[:,0:64]  (writes CT cols [128:192):
  //         disjoint from this stage's reads -> no mid barrier)
  if (wv < 4) {
    layerW<4,1,0>(CT,SCT, wp, F_L8, wv, lane, pbh,pbl, MR,SMR,0, CT,SCT, nullptr,0);
  }
  if (wv < 2) PFB(F_L9, wv, 2);
  else if (wv < 4) PFB(F_L10, wv - 2, 1);
  LBAR();

  // ---- S8 (fused): L9 (COT=2, waves 0-1): x1(MR[0:64]) -> CT[:,0:32]
  //                  L10 (COT=2, waves 2-3): lat1(E1)    -> CT[:,32:64]
  if (wv < 2) {
    layerW<2,0,0>(MR,SMR, wp, F_L9, wv, lane, pbh,pbl, CT,SCT,0,  nullptr,0, nullptr,0);
  } else if (wv < 4) {
    layerW<1,0,0>(E1,SE1, wp, F_L10, wv - 2, lane, pbh,pbl, CT,SCT,32, nullptr,0, nullptr,0);
  }
  if (wv < 2) PFB(F_L11, wv, 2);
  LBAR();

  // ---- S9: L11 (COT=2): merge1(CT[0:64]) + red -> MR[:,0:32]  (writes CT cols [128:160):
  //         disjoint from reads)
  if (wv < 2) {
    layerW<2,1,0>(CT,SCT, wp, F_L11, wv, lane, pbh,pbl, MR,SMR,0, CT,SCT, nullptr,0);
    PFB(F_L12, wv, 1);
  }
  LBAR();

  // ---- S10: L12 (COT=2): out(MR[0:32]) -> global fp32 [N,32]
  if (wv < 2) {
    layerW<1,2,0>(MR,SMR, wp, F_L12, wv, lane, pbh,pbl, nullptr,0,0, nullptr,0, out, row0);
  }
}

extern "C" void kernel_launch(void* const* d_in, const int* in_sizes, int n_in,
                              void* d_out, int out_size, void* d_ws, size_t ws_size,
                              hipStream_t stream) {
  (void)in_sizes; (void)n_in; (void)out_size; (void)ws_size;
  u16* packed = (u16*)d_ws;   // 352256 B

  // order: in, enc1, enc2, enc3, lat3, merge3, up3, lat2, merge2, up2, lat1, merge1, up1
  hipLaunchKernelGGL(pack_w, dim3(43), dim3(256), 0, stream,
      (const float*)d_in[2],  (const float*)d_in[3],  (const float*)d_in[4],
      (const float*)d_in[5],  (const float*)d_in[8],  (const float*)d_in[11],
      (const float*)d_in[14], (const float*)d_in[7],  (const float*)d_in[10],
      (const float*)d_in[13], (const float*)d_in[6],  (const float*)d_in[9],
      (const float*)d_in[12], packed);

  hipLaunchKernelGGL(backbone, dim3(NPAIRS), dim3(512), 0, stream,
                     (const float*)d_in[0], (const h16*)packed, (float*)d_out);
}